// Round 1
// baseline (60.787 us; speedup 1.0000x reference)
//
#include <hip/hip_runtime.h>
#include <stdint.h>

// Problem constants (B=4, T=1024, D=64 fixed by the reference setup)
#define TT  1024
#define DD  64
#define BB  4
#define BQ  8          // query rows per block
#define NTH 256        // threads per block (4 waves)

__device__ __forceinline__ uint32_t rotl32(uint32_t x, int d) {
  return (x << d) | (x >> (32 - d));
}

// Threefry-2x32, 20 rounds, key = (0, 42)  [jax.random.key(42)]
__device__ __forceinline__ void tf2x32(uint32_t x0, uint32_t x1,
                                       uint32_t& o0, uint32_t& o1) {
  const uint32_t ks0 = 0u, ks1 = 42u;
  const uint32_t ks2 = 0x1BD11BDAu ^ ks0 ^ ks1;
  x0 += ks0; x1 += ks1;
#define R4(a,b,c,d)                              \
  x0 += x1; x1 = rotl32(x1,(a)); x1 ^= x0;       \
  x0 += x1; x1 = rotl32(x1,(b)); x1 ^= x0;       \
  x0 += x1; x1 = rotl32(x1,(c)); x1 ^= x0;       \
  x0 += x1; x1 = rotl32(x1,(d)); x1 ^= x0;
  R4(13,15,26,6)   x0 += ks1; x1 += ks2 + 1u;
  R4(17,29,16,24)  x0 += ks2; x1 += ks0 + 2u;
  R4(13,15,26,6)   x0 += ks0; x1 += ks1 + 3u;
  R4(17,29,16,24)  x0 += ks1; x1 += ks2 + 4u;
  R4(13,15,26,6)   x0 += ks2; x1 += ks0 + 5u;
#undef R4
  o0 = x0; o1 = x1;
}

// JAX partitionable threefry random_bits(32) at flat index i:
// counter = uint64(i) -> (hi,lo) = (0, i); bits = out0 ^ out1.
// uniform = bitcast((bits>>9)|0x3f800000) - 1.0f ; keep = uniform < 0.8f
__device__ __forceinline__ bool keep_at(uint32_t i) {
  uint32_t o0, o1;
  tf2x32(0u, i, o0, o1);
  const uint32_t bits = o0 ^ o1;
  const float u = __uint_as_float((bits >> 9) | 0x3f800000u) - 1.0f;
  return u < 0.8f;
}

__global__ __launch_bounds__(NTH)
void attn_drop_kernel(const float* __restrict__ Q, const float* __restrict__ K,
                      float* __restrict__ O) {
  __shared__ float qs[BQ * DD];        // 2 KB
  __shared__ float ss[BQ][TT];         // 32 KB (scores, then exp values)
  __shared__ float rowScale[BQ];       // 1.25 / sum(exp)

  const int tid = threadIdx.x;
  const int rowBlocks = TT / BQ;                 // 128
  const int b    = blockIdx.x / rowBlocks;
  const int q0   = (blockIdx.x % rowBlocks) * BQ;
  const int jmax = q0 + BQ - 1;

  // ---- load Q tile (BQ*DD = 512 floats), coalesced ----
  {
    const float* qb = Q + ((size_t)b * TT + q0) * DD;
    for (int t = tid; t < BQ * DD; t += NTH) qs[t] = qb[t];
  }
  __syncthreads();

  // ---- Phase A: scores. Each thread owns key columns j = tid + 256*i.
  // k-row lives in 64 VGPRs, reused across all BQ query rows (k read once/block).
  const float scale = 0.125f;  // 64^-0.5
  for (int i = 0; i < TT / NTH; ++i) {
    const int j = tid + i * NTH;
    if (j <= jmax) {
      float4 kv[DD / 4];
      const float4* kb =
          reinterpret_cast<const float4*>(K + ((size_t)b * TT + j) * DD);
#pragma unroll
      for (int d = 0; d < DD / 4; ++d) kv[d] = kb[d];
#pragma unroll
      for (int r = 0; r < BQ; ++r) {
        const float4* qb4 = reinterpret_cast<const float4*>(qs + r * DD);
        float acc = 0.f;
#pragma unroll
        for (int d = 0; d < DD / 4; ++d) {
          const float4 qv = qb4[d];   // broadcast LDS read (all lanes same addr)
          acc = fmaf(qv.x, kv[d].x, acc);
          acc = fmaf(qv.y, kv[d].y, acc);
          acc = fmaf(qv.z, kv[d].z, acc);
          acc = fmaf(qv.w, kv[d].w, acc);
        }
        ss[r][j] = acc * scale;
      }
    }
  }
  __syncthreads();

  // ---- Phase B: per-row max + exp + sum (wave w handles rows w, w+4) ----
  const int wv = tid >> 6, ln = tid & 63;
  for (int r = wv; r < BQ; r += 4) {
    const int qrow = q0 + r;
    const int nk   = qrow + 1;       // causal: keys 0..qrow valid
    float m = -3.4e38f;
#pragma unroll
    for (int i = 0; i < TT / 64; ++i) {
      const int j = ln + i * 64;
      if (j < nk) m = fmaxf(m, ss[r][j]);
    }
#pragma unroll
    for (int off = 32; off; off >>= 1) m = fmaxf(m, __shfl_xor(m, off));
    float s = 0.f;
#pragma unroll
    for (int i = 0; i < TT / 64; ++i) {
      const int j = ln + i * 64;
      if (j < nk) {
        const float e = __expf(ss[r][j] - m);
        ss[r][j] = e;
        s += e;
      }
    }
#pragma unroll
    for (int off = 32; off; off >>= 1) s += __shfl_xor(s, off);
    if (ln == 0) rowScale[r] = 1.25f / s;   // includes /(1-p) dropout scale
  }
  __syncthreads();

  // ---- Phase C: write probs with deterministic dropout, coalesced ----
  for (int r = 0; r < BQ; ++r) {
    const int qrow  = q0 + r;
    const float sc  = rowScale[r];
    const size_t base = ((size_t)b * TT + qrow) * TT;
    for (int i = 0; i < TT / NTH; ++i) {
      const int j = tid + i * NTH;
      float v = 0.f;
      if (j <= qrow) {
        v = keep_at((uint32_t)(base + (size_t)j)) ? ss[r][j] * sc : 0.f;
      }
      O[base + j] = v;   // masked positions written as 0 (d_out is poisoned)
    }
  }
}

extern "C" void kernel_launch(void* const* d_in, const int* in_sizes, int n_in,
                              void* d_out, int out_size, void* d_ws, size_t ws_size,
                              hipStream_t stream) {
  const float* q = (const float*)d_in[0];
  const float* k = (const float*)d_in[1];
  // d_in[2] = T (1024), d_in[3] = block_size (1024): fixed, hardcoded above.
  float* out = (float*)d_out;
  const dim3 grid(BB * (TT / BQ));   // 512 blocks
  attn_drop_kernel<<<grid, NTH, 0, stream>>>(q, k, out);
}